// Round 15
// baseline (992.757 us; speedup 1.0000x reference)
//
#include <hip/hip_runtime.h>
#include <hip/hip_bf16.h>
#include <stdint.h>

#define V 32000
#define E 256
#define H 256
#define KCTX 3
#define S 2048
#define B 4
#define M (S * B)      // 8192 rows
#define K1 (KCTX * E)  // 768

typedef __attribute__((ext_vector_type(8))) short s16x8;
typedef __attribute__((ext_vector_type(4))) short s16x4;
typedef __attribute__((ext_vector_type(4))) float f32x4;

typedef const __attribute__((address_space(1))) unsigned short* gas_t;
typedef __attribute__((address_space(3))) unsigned short* las_t;

static __device__ __forceinline__ unsigned short f2bf(float f) {
  union { float f; unsigned u; } v; v.f = f;
  unsigned u = v.u;
  unsigned r = (u + 0x7fffu + ((u >> 16) & 1u)) >> 16;  // RNE
  return (unsigned short)r;
}

// ---------------------------------------------------------------------------
// Transpose + cast: in (R x C) f32  ->  out (C x R) bf16.  (used for w1 only)
// ---------------------------------------------------------------------------
__global__ void k_transpose_cast(const float* __restrict__ in,
                                 unsigned short* __restrict__ out,
                                 int R, int C) {
  __shared__ float tile[32][33];
  int bx = blockIdx.x;               // column-tile
  int by = blockIdx.y;               // row-tile
  int tx = threadIdx.x & 31;
  int ty = threadIdx.x >> 5;         // 0..7
#pragma unroll
  for (int i = 0; i < 32; i += 8)
    tile[ty + i][tx] = in[(size_t)(by * 32 + ty + i) * C + bx * 32 + tx];
  __syncthreads();
#pragma unroll
  for (int i = 0; i < 32; i += 8)
    out[(size_t)(bx * 32 + ty + i) * R + by * 32 + tx] = f2bf(tile[tx][ty + i]);
}

// ---------------------------------------------------------------------------
// Fused prep: blocks [0,8000) transpose w2 (f32 HxV) -> w2T (bf16 VxH);
// blocks [8000,8512) run stage1 (h = silu(x@w1+b1)). Independent work —
// overlapping them fills the BW the partial-line transpose writes leave idle.
// ---------------------------------------------------------------------------
__global__ __launch_bounds__(256) void k_prep(
    const int* __restrict__ tok, const float* __restrict__ embed,
    const unsigned short* __restrict__ w1T, const float* __restrict__ b1,
    unsigned short* __restrict__ hbuf,
    const float* __restrict__ w2, unsigned short* __restrict__ w2T) {
  __shared__ __align__(16) char smem[25088];
  int bid = blockIdx.x;
  int t = threadIdx.x;

  if (bid < 8000) {
    // ---- w2 transpose tile: bx over V/32 (1000), by over H/32 (8) ----
    float(*tile)[33] = reinterpret_cast<float(*)[33]>(smem);
    int bx = bid % 1000, by = bid / 1000;
    int tx = t & 31, ty = t >> 5;
#pragma unroll
    for (int i = 0; i < 32; i += 8)
      tile[ty + i][tx] = w2[(size_t)(by * 32 + ty + i) * V + bx * 32 + tx];
    __syncthreads();
#pragma unroll
    for (int i = 0; i < 32; i += 8)
      w2T[(size_t)(bx * 32 + ty + i) * H + by * 32 + tx] = f2bf(tile[tx][ty + i]);
    return;
  }

  // ---- stage1: one 16-row M-tile per block ----
  unsigned short(*xlds)[K1 + 8] =
      reinterpret_cast<unsigned short(*)[K1 + 8]>(smem);
  int* toks = reinterpret_cast<int*>(smem + 16 * (K1 + 8) * 2);  // 48 ints
  int m0 = (bid - 8000) * 16;

  if (t < 48) {
    int r = t / 3, kk = t - r * 3;
    int m = m0 + r, s = m >> 2, bb = m & 3;
    int tp = s - KCTX + kk;
    toks[t] = (tp >= 0) ? tok[tp * B + bb] : 0;
  }
  __syncthreads();

#pragma unroll
  for (int j = 0; j < 12; j++) {
    int c = j * 256 + t;
    int r = c / 192;           // 192 float4 per x-row
    int cc = c - r * 192;      // 0..191
    int kk = cc >> 6;
    int e4 = cc & 63;
    f32x4 v = *reinterpret_cast<const f32x4*>(
        embed + (size_t)toks[r * 3 + kk] * E + e4 * 4);
    s16x4 o;
#pragma unroll
    for (int jj = 0; jj < 4; jj++) o[jj] = (short)f2bf(v[jj]);
    *reinterpret_cast<s16x4*>(&xlds[r][cc * 4]) = o;
  }
  __syncthreads();

  int l = t & 63;
  int wv = t >> 6;
  int n0 = wv * 64;

  f32x4 zero = {0.f, 0.f, 0.f, 0.f};
  f32x4 acc[4];
#pragma unroll
  for (int ni = 0; ni < 4; ni++) acc[ni] = zero;

#pragma unroll
  for (int kt = 0; kt < 24; kt++) {
    s16x8 a = *reinterpret_cast<const s16x8*>(&xlds[l & 15][kt * 32 + (l >> 4) * 8]);
#pragma unroll
    for (int ni = 0; ni < 4; ni++) {
      int n = n0 + ni * 16 + (l & 15);
      s16x8 bf = *reinterpret_cast<const s16x8*>(
          w1T + (size_t)n * K1 + kt * 32 + (l >> 4) * 8);
      acc[ni] = __builtin_amdgcn_mfma_f32_16x16x32_bf16(a, bf, acc[ni], 0, 0, 0);
    }
  }

  int rbase = m0 + (l >> 4) * 4;
#pragma unroll
  for (int ni = 0; ni < 4; ni++) {
    int n = n0 + ni * 16 + (l & 15);
    float bias = b1[n];
#pragma unroll
    for (int j = 0; j < 4; j++) {
      float vv = acc[ni][j] + bias;
      float sv = vv / (1.0f + __expf(-vv));
      hbuf[(size_t)(rbase + j) * H + n] = f2bf(sv);
    }
  }
}

// ---------------------------------------------------------------------------
// Stage 2: out = h @ w2 + b2  (8192 x 32000, K=256).
// R12 machinery (256x128, 8 waves, BK=32, syncthreads schedule, fpatch
// nt-epilogue, B-reuse mapping) with a VGPR DIET to reach 3 blocks/CU:
// compute holds only 2 B-frags + 1 A-frag (64 acc + 12 frag + addr ~= 84);
// swizzle reduced to its lane-only invariant ((l&15)>>1)&3 (mi/ni/wv/j all
// drop out of (row>>1)&3 by algebra); global/LDS bases hoisted.
// __launch_bounds__(512,6): 24 waves/CU = 3 blocks -> write-queue duty up
// (2 blocks left it idle ~32% of the time => 225us vs 154us floor).
// Spills, if any, are CORRECT here (full __syncthreads fences — no counted
// vmcnt to miscount), just slow; the bench verdict attributes cleanly.
// ---------------------------------------------------------------------------
__global__ __launch_bounds__(512, 6) void k_stage2(
    const unsigned short* __restrict__ hbuf,  // (8192 x 256) bf16
    const unsigned short* __restrict__ w2T,   // (32000 x 256) bf16
    const float* __restrict__ b2, float* __restrict__ out) {
  __shared__ unsigned short lds[2][12288];  // per buf: A 256x32 + B 128x32

  int bid = blockIdx.x;
  int xcd = bid & 7;               // dispatch round-robins XCDs
  int i = bid >> 3;                // 0..999 within XCD
  int mtile = xcd * 4 + (i & 3);   // 4 mtiles per XCD, cycled fastest
  int ntile = i >> 2;              // 250 ntiles; B-tile shared by 4 blocks
  int m_base = mtile * 256, n_base = ntile * 128;

  int t = threadIdx.x;
  int l = t & 63;
  int wv = t >> 6;                // 0..7
  int wm = wv >> 1, wn = wv & 1;  // 4x2 wave grid; wave computes 64x64

  int srow = l >> 2;   // staging: lane's row within a 16-row call (64B rows)
  int c4 = l & 3;      // staging: lane's 16B chunk within a 64B row
  int sswz = (srow >> 1) & 3;     // staging swizzle (j/wv-independent)

  // hoisted per-lane global staging bases (tt adds +tt*32, j adds +j*4096)
  const unsigned short* ha =
      hbuf + (size_t)(m_base + wv * 32 + srow) * 256 + (c4 ^ sswz) * 8;
  const unsigned short* hb =
      w2T + (size_t)(n_base + wv * 16 + srow) * 256 + (c4 ^ sswz) * 8;

  // hoisted per-lane LDS read offsets (halfwords); mi/ni add +k*512
  int cswz = ((l & 15) >> 1) & 3;  // ds-read swizzle (mi/ni-independent)
  int ck = l >> 4;                 // lane's K-chunk
  int a_off = (wm * 64 + (l & 15)) * 32 + ((ck ^ cswz) * 8);
  int b_off = 8192 + (wn * 64 + (l & 15)) * 32 + ((ck ^ cswz) * 8);

  f32x4 zero = {0.f, 0.f, 0.f, 0.f};
  f32x4 acc[4][4];
#pragma unroll
  for (int mi = 0; mi < 4; mi++)
#pragma unroll
    for (int ni = 0; ni < 4; ni++) acc[mi][ni] = zero;

  auto stage = [&](int tt, int p) {
#pragma unroll
    for (int j = 0; j < 2; j++)            // A: 256 rows
      __builtin_amdgcn_global_load_lds((gas_t)(ha + tt * 32 + j * 4096),
                                       (las_t)&lds[p][(wv * 32 + j * 16) * 32],
                                       16, 0, 0);
    __builtin_amdgcn_global_load_lds((gas_t)(hb + tt * 32),  // B: 128 rows
                                     (las_t)&lds[p][8192 + (wv * 16) * 32],
                                     16, 0, 0);
  };

  auto compute = [&](int p) {
    const unsigned short* base = &lds[p][0];
#pragma unroll
    for (int half = 0; half < 2; half++) {
      s16x8 bf0 = *reinterpret_cast<const s16x8*>(base + b_off + (half * 2) * 512);
      s16x8 bf1 = *reinterpret_cast<const s16x8*>(base + b_off + (half * 2 + 1) * 512);
#pragma unroll
      for (int mi = 0; mi < 4; mi++) {
        s16x8 af = *reinterpret_cast<const s16x8*>(base + a_off + mi * 512);
        acc[mi][half * 2] =
            __builtin_amdgcn_mfma_f32_16x16x32_bf16(af, bf0, acc[mi][half * 2], 0, 0, 0);
        acc[mi][half * 2 + 1] =
            __builtin_amdgcn_mfma_f32_16x16x32_bf16(af, bf1, acc[mi][half * 2 + 1], 0, 0, 0);
      }
    }
  };

  stage(0, 0);
  __syncthreads();
#pragma unroll
  for (int tt = 0; tt < 8; tt++) {
    if (tt < 7) stage(tt + 1, (tt + 1) & 1);  // prefetch: flies during compute
    compute(tt & 1);
    __syncthreads();  // full fence: loads landed + all reads of buf done
  }
  __syncthreads();  // fpatch overlaps lds[1]: all compute(7) reads done first

  // epilogue: + b2, bounce through wave-private LDS patch, then nt-store
  // 256B-contiguous row segments (full 128B lines per transaction).
  float* fpatch = reinterpret_cast<float*>(&lds[0][0]) + wv * 1088;  // [16][68]
  int q = l >> 4, r = l & 15;
  float bias[4];
#pragma unroll
  for (int ni = 0; ni < 4; ni++)
    bias[ni] = b2[n_base + wn * 64 + ni * 16 + r];

#pragma unroll
  for (int mi = 0; mi < 4; mi++) {
#pragma unroll
    for (int ni = 0; ni < 4; ni++)
#pragma unroll
      for (int j = 0; j < 4; j++)
        fpatch[(q * 4 + j) * 68 + ni * 16 + r] = acc[mi][ni][j] + bias[ni];
#pragma unroll
    for (int it = 0; it < 4; it++) {
      int row16 = it * 4 + q;     // 4 rows per instr, 16 lanes per row
      f32x4 v = *reinterpret_cast<const f32x4*>(fpatch + row16 * 68 + r * 4);
      float* dst = &out[(size_t)(m_base + wm * 64 + mi * 16 + row16) * V +
                        n_base + wn * 64 + r * 4];
      __builtin_nontemporal_store(v, reinterpret_cast<f32x4*>(dst));
    }
  }
}

// ---------------------------------------------------------------------------
extern "C" void kernel_launch(void* const* d_in, const int* in_sizes, int n_in,
                              void* d_out, int out_size, void* d_ws,
                              size_t ws_size, hipStream_t stream) {
  const int* tokens = (const int*)d_in[0];     // (S, B)
  const float* embed = (const float*)d_in[1];  // (V, E)
  const float* w1 = (const float*)d_in[2];     // (K1, H)
  const float* b1 = (const float*)d_in[3];     // (H)
  const float* w2 = (const float*)d_in[4];     // (H, V)
  const float* b2 = (const float*)d_in[5];     // (V)
  float* out = (float*)d_out;

  unsigned short* w2T = (unsigned short*)d_ws;          // V*E   bf16
  unsigned short* w1T = w2T + (size_t)V * E;            // H*K1  bf16
  unsigned short* hb  = w1T + (size_t)H * K1;           // M*H   bf16

  // w1T first (tiny); then fused w2-transpose + stage1; then stage2.
  k_transpose_cast<<<dim3(H / 32, K1 / 32), 256, 0, stream>>>(w1, w1T, K1, H);
  k_prep<<<8512, 256, 0, stream>>>(tokens, embed, w1T, b1, hb, w2, w2T);
  k_stage2<<<8000, 512, 0, stream>>>(hb, w2T, b2, out);
}

// Round 16
// 270.414 us; speedup vs baseline: 3.6712x; 3.6712x over previous
//
#include <hip/hip_runtime.h>
#include <hip/hip_bf16.h>
#include <stdint.h>

#define V 32000
#define E 256
#define H 256
#define KCTX 3
#define S 2048
#define B 4
#define M (S * B)      // 8192 rows
#define K1 (KCTX * E)  // 768

typedef __attribute__((ext_vector_type(8))) short s16x8;
typedef __attribute__((ext_vector_type(4))) short s16x4;
typedef __attribute__((ext_vector_type(4))) float f32x4;

typedef const __attribute__((address_space(1))) unsigned short* gas_t;
typedef __attribute__((address_space(3))) unsigned short* las_t;

static __device__ __forceinline__ unsigned short f2bf(float f) {
  union { float f; unsigned u; } v; v.f = f;
  unsigned u = v.u;
  unsigned r = (u + 0x7fffu + ((u >> 16) & 1u)) >> 16;  // RNE
  return (unsigned short)r;
}

// ---------------------------------------------------------------------------
// Transpose + cast: in (R x C) f32  ->  out (C x R) bf16.  R%32==0, C%32==0.
// ---------------------------------------------------------------------------
__global__ void k_transpose_cast(const float* __restrict__ in,
                                 unsigned short* __restrict__ out,
                                 int R, int C) {
  __shared__ float tile[32][33];
  int bx = blockIdx.x;               // column-tile
  int by = blockIdx.y;               // row-tile
  int tx = threadIdx.x & 31;
  int ty = threadIdx.x >> 5;         // 0..7
#pragma unroll
  for (int i = 0; i < 32; i += 8)
    tile[ty + i][tx] = in[(size_t)(by * 32 + ty + i) * C + bx * 32 + tx];
  __syncthreads();
#pragma unroll
  for (int i = 0; i < 32; i += 8)
    out[(size_t)(bx * 32 + ty + i) * R + by * 32 + tx] = f2bf(tile[tx][ty + i]);
}

// ---------------------------------------------------------------------------
// Stage 1: h = silu(x @ w1 + b1), h bf16 (8192 x 256).
// Block = 4 waves = one 16-row M-tile; x-tile gathered once into LDS.
// ---------------------------------------------------------------------------
__global__ __launch_bounds__(256) void k_stage1(
    const int* __restrict__ tok, const float* __restrict__ embed,
    const unsigned short* __restrict__ w1T,  // (H x K1) bf16, w1T[n][k]
    const float* __restrict__ b1, unsigned short* __restrict__ hbuf) {
  __shared__ unsigned short xlds[16][K1 + 8];
  __shared__ int toks[48];
  int bid = blockIdx.x;        // 0..511
  int t = threadIdx.x;
  int m0 = bid * 16;

  if (t < 48) {
    int r = t / 3, kk = t - r * 3;
    int m = m0 + r, s = m >> 2, bb = m & 3;
    int tp = s - KCTX + kk;
    toks[t] = (tp >= 0) ? tok[tp * B + bb] : 0;
  }
  __syncthreads();

#pragma unroll
  for (int j = 0; j < 12; j++) {
    int c = j * 256 + t;
    int r = c / 192;           // 192 float4 per x-row
    int cc = c - r * 192;      // 0..191
    int kk = cc >> 6;
    int e4 = cc & 63;
    f32x4 v = *reinterpret_cast<const f32x4*>(
        embed + (size_t)toks[r * 3 + kk] * E + e4 * 4);
    s16x4 o;
#pragma unroll
    for (int jj = 0; jj < 4; jj++) o[jj] = (short)f2bf(v[jj]);
    *reinterpret_cast<s16x4*>(&xlds[r][cc * 4]) = o;
  }
  __syncthreads();

  int l = t & 63;
  int wv = t >> 6;
  int n0 = wv * 64;

  f32x4 zero = {0.f, 0.f, 0.f, 0.f};
  f32x4 acc[4];
#pragma unroll
  for (int ni = 0; ni < 4; ni++) acc[ni] = zero;

#pragma unroll
  for (int kt = 0; kt < 24; kt++) {
    s16x8 a = *reinterpret_cast<const s16x8*>(&xlds[l & 15][kt * 32 + (l >> 4) * 8]);
#pragma unroll
    for (int ni = 0; ni < 4; ni++) {
      int n = n0 + ni * 16 + (l & 15);
      s16x8 bf = *reinterpret_cast<const s16x8*>(
          w1T + (size_t)n * K1 + kt * 32 + (l >> 4) * 8);
      acc[ni] = __builtin_amdgcn_mfma_f32_16x16x32_bf16(a, bf, acc[ni], 0, 0, 0);
    }
  }

  int rbase = m0 + (l >> 4) * 4;
#pragma unroll
  for (int ni = 0; ni < 4; ni++) {
    int n = n0 + ni * 16 + (l & 15);
    float bias = b1[n];
#pragma unroll
    for (int j = 0; j < 4; j++) {
      float vv = acc[ni][j] + bias;
      float sv = vv / (1.0f + __expf(-vv));
      hbuf[(size_t)(rbase + j) * H + n] = f2bf(sv);
    }
  }
}

// ---------------------------------------------------------------------------
// Stage 2: out = h @ w2 + b2  (8192 x 32000, K=256).
// EXACT round-12 configuration (best: 270.9 us). R13 (smaller tile), R14
// (counted vmcnt), R15 (VGPR diet -> 40-VGPR spill disaster, 933 us) all
// failed to beat it. 64x64/wave => 64-VGPR acc => >=128 VGPR structural =>
// 2 blocks/CU is a hard floor at this tile shape.
// ---------------------------------------------------------------------------
__global__ __launch_bounds__(512, 4) void k_stage2(
    const unsigned short* __restrict__ hbuf,  // (8192 x 256) bf16
    const unsigned short* __restrict__ w2T,   // (32000 x 256) bf16
    const float* __restrict__ b2, float* __restrict__ out) {
  __shared__ unsigned short lds[2][12288];  // per buf: A 256x32 (8192) + B 128x32 (4096)

  int bid = blockIdx.x;
  int xcd = bid & 7;               // dispatch round-robins XCDs
  int i = bid >> 3;                // 0..999 within XCD
  int mtile = xcd * 4 + (i & 3);   // 4 mtiles per XCD, cycled fastest
  int ntile = i >> 2;              // 250 ntiles; B-tile shared by 4 blocks
  int m_base = mtile * 256, n_base = ntile * 128;

  int t = threadIdx.x;
  int l = t & 63;
  int wv = t >> 6;                // 0..7
  int wm = wv >> 1, wn = wv & 1;  // 4x2 wave grid; wave computes 64x64

  int srow = l >> 2;   // lane's row within a 16-row staging call (64B rows)
  int c4 = l & 3;      // lane's 16B chunk within a 64B row

  f32x4 zero = {0.f, 0.f, 0.f, 0.f};
  f32x4 acc[4][4];
#pragma unroll
  for (int mi = 0; mi < 4; mi++)
#pragma unroll
    for (int ni = 0; ni < 4; ni++) acc[mi][ni] = zero;

  // stage K-slice tt (BK=32) into buffer p: 3 gload_lds per wave.
  // Global source chunk is XOR-permuted so linear LDS dest leaves data at
  // chunk (c ^ ((row>>1)&3))  [rule 21: swizzle both sides or neither].
  auto stage = [&](int tt, int p) {
    int gk = tt * 32;
#pragma unroll
    for (int j = 0; j < 2; j++) {          // A: 256 rows
      int r0 = wv * 32 + j * 16;
      int row = r0 + srow;
      int gc = c4 ^ ((row >> 1) & 3);
      const unsigned short* ga =
          hbuf + (size_t)(m_base + row) * 256 + gk + gc * 8;
      __builtin_amdgcn_global_load_lds((gas_t)ga, (las_t)&lds[p][r0 * 32], 16, 0, 0);
    }
    {                                      // B: 128 rows
      int r0 = wv * 16;
      int row = r0 + srow;
      int gc = c4 ^ ((row >> 1) & 3);
      const unsigned short* gb =
          w2T + (size_t)(n_base + row) * 256 + gk + gc * 8;
      __builtin_amdgcn_global_load_lds((gas_t)gb, (las_t)&lds[p][8192 + r0 * 32], 16, 0, 0);
    }
  };

  auto compute = [&](int p) {
    const unsigned short* bufA = &lds[p][0];
    const unsigned short* bufB = &lds[p][8192];
    int c = l >> 4;  // lane's K-chunk (0..3)
    s16x8 af[4], bfr[4];
#pragma unroll
    for (int mi = 0; mi < 4; mi++) {
      int row = wm * 64 + mi * 16 + (l & 15);
      af[mi] = *reinterpret_cast<const s16x8*>(
          bufA + row * 32 + (c ^ ((row >> 1) & 3)) * 8);
    }
#pragma unroll
    for (int ni = 0; ni < 4; ni++) {
      int row = wn * 64 + ni * 16 + (l & 15);
      bfr[ni] = *reinterpret_cast<const s16x8*>(
          bufB + row * 32 + (c ^ ((row >> 1) & 3)) * 8);
    }
#pragma unroll
    for (int mi = 0; mi < 4; mi++)
#pragma unroll
      for (int ni = 0; ni < 4; ni++)
        acc[mi][ni] = __builtin_amdgcn_mfma_f32_16x16x32_bf16(
            af[mi], bfr[ni], acc[mi][ni], 0, 0, 0);
  };

  stage(0, 0);
  __syncthreads();
#pragma unroll
  for (int tt = 0; tt < 8; tt++) {
    if (tt < 7) stage(tt + 1, (tt + 1) & 1);  // prefetch: flies during compute
    compute(tt & 1);
    __syncthreads();  // full fence: loads landed + all reads of buf done
  }
  __syncthreads();  // fpatch overlaps lds[1]: all compute(7) reads done first

  // epilogue: + b2, bounce through wave-private LDS patch, then nt-store
  // 256B-contiguous row segments (full 128B lines per transaction).
  float* fpatch = reinterpret_cast<float*>(&lds[0][0]) + wv * 1088;  // [16][68]
  int q = l >> 4, r = l & 15;
  float bias[4];
#pragma unroll
  for (int ni = 0; ni < 4; ni++)
    bias[ni] = b2[n_base + wn * 64 + ni * 16 + r];

#pragma unroll
  for (int mi = 0; mi < 4; mi++) {
    // scatter acc[mi] (+bias) into patch: row q*4+j, col ni*16+r  (2-way: free)
#pragma unroll
    for (int ni = 0; ni < 4; ni++)
#pragma unroll
      for (int j = 0; j < 4; j++)
        fpatch[(q * 4 + j) * 68 + ni * 16 + r] = acc[mi][ni][j] + bias[ni];
    // read back row-major (wave-private: no barrier; lgkmcnt by compiler)
#pragma unroll
    for (int it = 0; it < 4; it++) {
      int row16 = it * 4 + q;     // 4 rows per instr, 16 lanes per row
      f32x4 v = *reinterpret_cast<const f32x4*>(fpatch + row16 * 68 + r * 4);
      float* dst = &out[(size_t)(m_base + wm * 64 + mi * 16 + row16) * V +
                        n_base + wn * 64 + r * 4];
      __builtin_nontemporal_store(v, reinterpret_cast<f32x4*>(dst));
    }
    // next mi overwrites the patch: same-wave DS ops are in-order -> safe
  }
}

// ---------------------------------------------------------------------------
extern "C" void kernel_launch(void* const* d_in, const int* in_sizes, int n_in,
                              void* d_out, int out_size, void* d_ws,
                              size_t ws_size, hipStream_t stream) {
  const int* tokens = (const int*)d_in[0];     // (S, B)
  const float* embed = (const float*)d_in[1];  // (V, E)
  const float* w1 = (const float*)d_in[2];     // (K1, H)
  const float* b1 = (const float*)d_in[3];     // (H)
  const float* w2 = (const float*)d_in[4];     // (H, V)
  const float* b2 = (const float*)d_in[5];     // (V)
  float* out = (float*)d_out;

  unsigned short* w2T = (unsigned short*)d_ws;          // V*E   bf16
  unsigned short* w1T = w2T + (size_t)V * E;            // H*K1  bf16
  unsigned short* hb  = w1T + (size_t)H * K1;           // M*H   bf16

  k_transpose_cast<<<dim3(V / 32, H / 32), 256, 0, stream>>>(w2, w2T, H, V);
  k_transpose_cast<<<dim3(H / 32, K1 / 32), 256, 0, stream>>>(w1, w1T, K1, H);
  k_stage1<<<512, 256, 0, stream>>>(tokens, embed, w1T, b1, hb);
  k_stage2<<<8000, 512, 0, stream>>>(hb, w2T, b2, out);
}